// Round 22
// baseline (95.594 us; speedup 1.0000x reference)
//
#include <hip/hip_runtime.h>
#include <hip/hip_bf16.h>

#define BATCH 2
#define SEQ 2048
#define DMODEL 1024
#define NHEADS 16
#define HDIM 64
#define NSPLIT 4
#define KVB 32
#define NIT (SEQ / NSPLIT / KVB)   // 16

// 0.125 (1/sqrt(64)) * log2(e): logits land directly in exp2 domain
#define QSCALE 0.180336880f
#define DEFER_THR 8.0f

typedef __bf16 bf16x8 __attribute__((ext_vector_type(8)));
typedef __bf16 bf16x4 __attribute__((ext_vector_type(4)));
typedef float f32x4 __attribute__((ext_vector_type(4)));
typedef float f32x16 __attribute__((ext_vector_type(16)));
typedef unsigned int uint2v __attribute__((ext_vector_type(2)));

union B8u { unsigned int u[4]; bf16x8 v; };

__device__ __forceinline__ unsigned int cvt_pk_bf16(float lo, float hi) {
  unsigned int d;
  asm("v_cvt_pk_bf16_f32 %0, %1, %2" : "=v"(d) : "v"(lo), "v"(hi));
  return d;
}

// a' = {a.lo32lanes, b.lo32lanes}; b' = {a.hi32lanes, b.hi32lanes}
__device__ __forceinline__ void permlane32_swap(unsigned &a, unsigned &b) {
  auto r = __builtin_amdgcn_permlane32_swap(a, b, false, false);
  unsigned tmp[2];
  __builtin_memcpy(tmp, &r, 8);
  a = tmp[0]; b = tmp[1];
}

// ---------------------------------------------------------------------------
// Fused prep (one launch) — byte-identical to R11/R17/R21 measured kernel.
// ---------------------------------------------------------------------------
__global__ __launch_bounds__(256)
void conv_all(const float* __restrict__ K, __bf16* __restrict__ Kbf,
              const float* __restrict__ V, __bf16* __restrict__ Vt,
              const float* __restrict__ W, __bf16* __restrict__ Wbf) {
  const int p = blockIdx.x;
  __shared__ __bf16 T[64][72];

  if (p < 2048) {
    const int t = p * 256 + threadIdx.x;
    const int d8 = t & 7, key = (t >> 3) & (SEQ - 1), g = t >> 14;
    const float* src = K + ((size_t)(g >> 4) * SEQ + key) * DMODEL +
                       (g & 15) * HDIM + d8 * 8;
    f32x4 a = *reinterpret_cast<const f32x4*>(src);
    f32x4 c = *reinterpret_cast<const f32x4*>(src + 4);
    bf16x8 o;
#pragma unroll
    for (int j = 0; j < 4; ++j) { o[j] = (__bf16)a[j]; o[4 + j] = (__bf16)c[j]; }
    *reinterpret_cast<bf16x8*>(Kbf + (size_t)t * 8) = o;
  } else if (p < 3072) {
    const int blk = p - 2048;                    // 1024
    const int g = blk >> 5, c0 = (blk & 31) * 64;
    const int b = g >> 4, h = g & 15;
    {
      const int key = threadIdx.x >> 2, dq = threadIdx.x & 3;
      const float* src = V + ((size_t)(b * SEQ) + c0 + key) * DMODEL +
                         h * HDIM + dq * 16;
#pragma unroll
      for (int i = 0; i < 4; ++i) {
        f32x4 v = *reinterpret_cast<const f32x4*>(src + 4 * i);
        bf16x4 o;
#pragma unroll
        for (int j = 0; j < 4; ++j) o[j] = (__bf16)v[j];
        *reinterpret_cast<bf16x4*>(&T[key][dq * 16 + 4 * i]) = o;
      }
    }
    __syncthreads();
    {
      const int d = threadIdx.x >> 2, kq = threadIdx.x & 3;
      bf16x8 r0, r1;
#pragma unroll
      for (int i = 0; i < 8; ++i) {
        r0[i] = T[kq * 16 + i][d];
        r1[i] = T[kq * 16 + 8 + i][d];
      }
      __bf16* dst = Vt + ((size_t)g * HDIM + d) * SEQ + c0 + kq * 16;
      *reinterpret_cast<bf16x8*>(dst) = r0;
      *reinterpret_cast<bf16x8*>(dst + 8) = r1;
    }
  } else {
    const int t = (p - 3072) * 256 + threadIdx.x;
    f32x4 a = *reinterpret_cast<const f32x4*>(W + (size_t)t * 8);
    f32x4 c = *reinterpret_cast<const f32x4*>(W + (size_t)t * 8 + 4);
    bf16x8 o;
#pragma unroll
    for (int j = 0; j < 4; ++j) { o[j] = (__bf16)a[j]; o[4 + j] = (__bf16)c[j]; }
    *reinterpret_cast<bf16x8*>(Wbf + (size_t)t * 8) = o;
  }
}

// ---------------------------------------------------------------------------
// Flash attention, 32x32 swapped structure, 4-way in-block KV-split,
// KVBLK=32, single-buffered LDS (register-carried prefetch), XCD swizzle.
// Block = 64 q-rows; 8 waves = (qg 0..1) x (ks 0..3); grid 1024 = 4 blk/CU.
// Split ks covers keys [ks*512, ks*512+512) in 16 chunks of 32.
// Fragment math = verified 32-key sub-path of the R17/R21 kernel.
// 3-round sequential merge via LDS (dumps alias dead K/V tiles).
// ---------------------------------------------------------------------------
__global__ __launch_bounds__(512, 4)
void attn_kernel(const float* __restrict__ Q, const __bf16* __restrict__ Kbf,
                 const __bf16* __restrict__ Vt, __bf16* __restrict__ O) {
  const int p = blockIdx.x;
  const int xcd = p & 7, slot = p >> 3;          // slot 0..127
  const int g = xcd + 8 * (slot >> 5);           // (b*16+h), 4 groups per XCD
  const int b = g >> 4, h = g & 15;
  const int q0 = (slot & 31) * 64;

  const int tid = threadIdx.x;
  const int wave = tid >> 6, lane = tid & 63;
  const int qg = wave & 1, ks = wave >> 1;       // ks == tid>>7 == staging split
  const int l31 = lane & 31, hi = lane >> 5;
  const int ob = hi << 4;
  const int swz = (l31 & 7) << 4;

  __shared__ __align__(16) __bf16 SK[4][32 * 64];   // 4KB/split, 128B rows
  __shared__ __align__(16) __bf16 SV[4][64 * 40];   // 5KB/split, 80B rows
  __shared__ float mlb[3][2][2][32];                // [dump][m/l][qg][q]

  const int qrow = q0 + (qg << 5) + l31;
  const float* qp = Q + ((size_t)(b * SEQ + qrow)) * DMODEL + h * HDIM;
  bf16x8 qf[4];
#pragma unroll
  for (int kd = 0; kd < 4; ++kd) {
    f32x4 a = *reinterpret_cast<const f32x4*>(qp + kd * 16 + hi * 8);
    f32x4 c = *reinterpret_cast<const f32x4*>(qp + kd * 16 + hi * 8 + 4);
#pragma unroll
    for (int j = 0; j < 4; ++j) {
      qf[kd][j]     = (__bf16)(a[j] * QSCALE);
      qf[kd][4 + j] = (__bf16)(c[j] * QSCALE);
    }
  }

  f32x16 oacc0, oacc1;
#pragma unroll
  for (int r = 0; r < 16; ++r) { oacc0[r] = 0.f; oacc1[r] = 0.f; }
  float m_run = -1e30f, l_run = 0.f;

  const __bf16* kgb = Kbf + (size_t)g * SEQ * HDIM;
  const __bf16* vgb = Vt + (size_t)g * HDIM * SEQ;

  // staging roles: 128 threads per split
  const int t2 = tid & 127;
  const int sk_key = t2 >> 2, sk_dq = t2 & 3;    // K: 32 keys x 16-dim quarters
  const int sv_dim = t2 >> 1, sv_kh = t2 & 1;    // V: 64 dims x 16-key halves
  const int ksw = (sk_key & 7) << 4;

  bf16x8 kr0, kr1, vr0, vr1;

#define STAGE_LOAD(C0)                                                        \
  do {                                                                        \
    const __bf16* kc = kgb + (size_t)((C0) + sk_key) * HDIM + sk_dq * 16;     \
    kr0 = *reinterpret_cast<const bf16x8*>(kc);                               \
    kr1 = *reinterpret_cast<const bf16x8*>(kc + 8);                           \
    const __bf16* vc = vgb + (size_t)sv_dim * SEQ + (C0) + sv_kh * 16;        \
    vr0 = *reinterpret_cast<const bf16x8*>(vc);                               \
    vr1 = *reinterpret_cast<const bf16x8*>(vc + 8);                           \
  } while (0)

#define STAGE_WRITE()                                                         \
  do {                                                                        \
    char* kdst = (char*)(&SK[ks][0]) + sk_key * 128;                          \
    *reinterpret_cast<bf16x8*>(kdst + (((sk_dq << 5)) ^ ksw)) = kr0;          \
    *reinterpret_cast<bf16x8*>(kdst + (((sk_dq << 5) | 16) ^ ksw)) = kr1;     \
    char* vdst = (char*)(&SV[ks][0]) + sv_dim * 80 + sv_kh * 32;              \
    *reinterpret_cast<bf16x8*>(vdst) = vr0;                                   \
    *reinterpret_cast<bf16x8*>(vdst + 16) = vr1;                              \
  } while (0)

  // prologue: chunk 0 -> LDS; chunk 1 -> regs
  STAGE_LOAD(ks * 512);
  STAGE_WRITE();
  __syncthreads();
  STAGE_LOAD(ks * 512 + KVB);

  for (int i = 0; i < NIT; ++i) {
    const char* kb = (const char*)(&SK[ks][0]);
    const char* vb = (const char*)(&SV[ks][0]);

    // --- QK^T swapped: S^T[key][qrow], 32 keys in one f32x16 ---
    f32x16 s;
#pragma unroll
    for (int r = 0; r < 16; ++r) s[r] = 0.f;
    __builtin_amdgcn_s_setprio(1);
#pragma unroll
    for (int kd = 0; kd < 4; ++kd) {
      bf16x8 a0 = *reinterpret_cast<const bf16x8*>(
          kb + l31 * 128 + (((kd << 5) | ob) ^ swz));
      s = __builtin_amdgcn_mfma_f32_32x32x16_bf16(a0, qf[kd], s, 0, 0, 0);
    }
    __builtin_amdgcn_s_setprio(0);

    // --- row max ---
    float m8[8];
#pragma unroll
    for (int r = 0; r < 8; ++r) m8[r] = fmaxf(s[r], s[r + 8]);
    float pm = fmaxf(fmaxf(fmaxf(m8[0], m8[1]), fmaxf(m8[2], m8[3])),
                     fmaxf(fmaxf(m8[4], m8[5]), fmaxf(m8[6], m8[7])));
    pm = fmaxf(pm, __shfl_xor(pm, 32, 64));

    // --- defer-max rescale (T13) ---
    if (!__all(pm <= m_run + DEFER_THR)) {
      float mu = fmaxf(m_run, pm);
      float al = __builtin_amdgcn_exp2f(m_run - mu);
      m_run = mu;
      l_run *= al;
#pragma unroll
      for (int r = 0; r < 16; ++r) { oacc0[r] *= al; oacc1[r] *= al; }
    }

    // --- P = exp2(S - m); row sum ---
#pragma unroll
    for (int r = 0; r < 16; ++r) s[r] = __builtin_amdgcn_exp2f(s[r] - m_run);
    float t8[8];
#pragma unroll
    for (int r = 0; r < 8; ++r) t8[r] = s[r] + s[r + 8];
    float ts = ((t8[0] + t8[1]) + (t8[2] + t8[3])) +
               ((t8[4] + t8[5]) + (t8[6] + t8[7]));
    ts += __shfl_xor(ts, 32, 64);
    l_run += ts;

    // --- pack P^T B-frags (8 cvt_pk + 4 permlane) ---
    B8u pfr[2];
#pragma unroll
    for (int kq = 0; kq < 2; ++kq) {
      const int r0 = kq * 8;
      unsigned lo0 = cvt_pk_bf16(s[r0 + 0], s[r0 + 1]);
      unsigned lo1 = cvt_pk_bf16(s[r0 + 2], s[r0 + 3]);
      unsigned h0  = cvt_pk_bf16(s[r0 + 4], s[r0 + 5]);
      unsigned h1  = cvt_pk_bf16(s[r0 + 6], s[r0 + 7]);
      permlane32_swap(lo0, h0);
      permlane32_swap(lo1, h1);
      pfr[kq].u[0] = lo0; pfr[kq].u[1] = lo1;
      pfr[kq].u[2] = h0;  pfr[kq].u[3] = h1;
    }

    // --- PV swapped ---
    __builtin_amdgcn_s_setprio(1);
#pragma unroll
    for (int kq = 0; kq < 2; ++kq) {
      bf16x8 v0 = *reinterpret_cast<const bf16x8*>(
          vb + l31 * 80 + ((kq << 5) | ob));
      bf16x8 v1 = *reinterpret_cast<const bf16x8*>(
          vb + (32 + l31) * 80 + ((kq << 5) | ob));
      oacc0 = __builtin_amdgcn_mfma_f32_32x32x16_bf16(v0, pfr[kq].v, oacc0, 0, 0, 0);
      oacc1 = __builtin_amdgcn_mfma_f32_32x32x16_bf16(v1, pfr[kq].v, oacc1, 0, 0, 0);
    }
    __builtin_amdgcn_s_setprio(0);

    __syncthreads();                         // all waves done reading chunk i
    if (i + 1 < NIT) {
      STAGE_WRITE();                         // publish chunk i+1
      if (i + 2 < NIT) STAGE_LOAD(ks * 512 + (i + 2) * KVB);
    }
    __syncthreads();                         // chunk i+1 visible
  }

  // ---- 3-round merge of 4 KV-splits (dumps alias dead K/V LDS) ----
  float* ObA = (float*)&SK[0][0];            // 16 KB = [2][64][32] fp32
  float* ObB = (float*)&SV[0][0];            // first 16 KB of SV

#define DUMP(OB, MI)                                                          \
  do {                                                                        \
    if (hi == 0) { mlb[MI][0][qg][l31] = m_run; mlb[MI][1][qg][l31] = l_run; }\
    _Pragma("unroll") for (int dt = 0; dt < 2; ++dt) {                        \
      f32x16 oa = dt ? oacc1 : oacc0;                                         \
      _Pragma("unroll") for (int r = 0; r < 16; ++r) {                        \
        int dim = dt * 32 + (r & 3) + 8 * (r >> 2) + 4 * hi;                  \
        (OB)[((qg << 6) + dim) * 32 + l31] = oa[r];                           \
      }                                                                       \
    }                                                                         \
  } while (0)

#define COMBINE(OB, MI)                                                       \
  do {                                                                        \
    float m1 = mlb[MI][0][qg][l31], l1 = mlb[MI][1][qg][l31];                 \
    float mm = fmaxf(m_run, m1);                                              \
    float a0 = __builtin_amdgcn_exp2f(m_run - mm);                            \
    float a1 = __builtin_amdgcn_exp2f(m1 - mm);                               \
    _Pragma("unroll") for (int dt = 0; dt < 2; ++dt) {                        \
      _Pragma("unroll") for (int r = 0; r < 16; ++r) {                        \
        int dim = dt * 32 + (r & 3) + 8 * (r >> 2) + 4 * hi;                  \
        float opart = (OB)[((qg << 6) + dim) * 32 + l31];                     \
        if (dt) oacc1[r] = oacc1[r] * a0 + opart * a1;                        \
        else    oacc0[r] = oacc0[r] * a0 + opart * a1;                        \
      }                                                                       \
    }                                                                         \
    l_run = l_run * a0 + l1 * a1;                                             \
    m_run = mm;                                                               \
  } while (0)

  if (ks == 1) DUMP(ObA, 0);
  if (ks == 2) DUMP(ObB, 1);
  __syncthreads();
  if (ks == 0) { COMBINE(ObA, 0); COMBINE(ObB, 1); }
  __syncthreads();
  if (ks == 3) DUMP(ObA, 2);
  __syncthreads();

  if (ks == 0) {
    COMBINE(ObA, 2);
    const float inv = 1.0f / l_run;
    __bf16* op = O + ((size_t)(b * SEQ + qrow)) * DMODEL + h * HDIM;
#pragma unroll
    for (int dt = 0; dt < 2; ++dt) {
      f32x16 oa = dt ? oacc1 : oacc0;
#pragma unroll
      for (int a = 0; a < 4; ++a) {
        uint2v w;
        w[0] = cvt_pk_bf16(oa[4 * a + 0] * inv, oa[4 * a + 1] * inv);
        w[1] = cvt_pk_bf16(oa[4 * a + 2] * inv, oa[4 * a + 3] * inv);
        *reinterpret_cast<uint2v*>((char*)op + (dt * 32 + a * 8 + hi * 4) * 2) = w;
      }
    }
  }
#undef STAGE_LOAD
#undef STAGE_WRITE
#undef DUMP
#undef COMBINE
}

// ---------------------------------------------------------------------------
// FC — byte-identical to R20/R21 measured kernel.
// ---------------------------------------------------------------------------
__global__ __launch_bounds__(256)
void fc_kernel(const __bf16* __restrict__ X, const __bf16* __restrict__ W,
               const float* __restrict__ bias, float* __restrict__ Y) {
  const int p = blockIdx.x;
  const int xcd = p & 7, slot = p >> 3;            // slot 0..63
  const int m0 = (xcd + 8 * (slot >> 4)) * 128;    // 4 m-tiles per XCD
  const int n0 = (slot & 15) * 64;

  const int tid = threadIdx.x;
  const int wave = tid >> 6, lane = tid & 63;
  const int g = lane >> 4, lr = lane & 15;
  const int wm = wave >> 1, wn = wave & 1;

  __shared__ __bf16 As[128][72];   // [m][k], +8 pad
  __shared__ __bf16 Bs[64][72];    // [n][k]

  f32x4 acc[4][2];
#pragma unroll
  for (int i = 0; i < 4; ++i)
#pragma unroll
    for (int j = 0; j < 2; ++j) acc[i][j] = (f32x4){0.f, 0.f, 0.f, 0.f};

  float bv[2];
#pragma unroll
  for (int j = 0; j < 2; ++j) bv[j] = bias[n0 + wn * 32 + 16 * j + lr];

  bf16x8 av[4], wv[2];

#define FC_LOAD(KK)                                                          \
  do {                                                                       \
    _Pragma("unroll") for (int e = 0; e < 4; ++e) {                          \
      int idx = tid + 256 * e;                                               \
      int row = idx >> 3, k8 = idx & 7;                                      \
      av[e] = *reinterpret_cast<const bf16x8*>(                              \
          X + (size_t)(m0 + row) * DMODEL + (KK) + k8 * 8);                  \
    }                                                                        \
    _Pragma("unroll") for (int e = 0; e < 2; ++e) {                          \
      int idx = tid + 256 * e;                                               \
      int row = idx >> 3, k8 = idx & 7;                                      \
      wv[e] = *reinterpret_cast<const bf16x8*>(                              \
          W + (size_t)(n0 + row) * DMODEL + (KK) + k8 * 8);                  \
    }                                                                        \
  } while (0)

#define FC_WRITE()                                                           \
  do {                                                                       \
    _Pragma("unroll") for (int e = 0; e < 4; ++e) {                          \
      int idx = tid + 256 * e;                                               \
      int row = idx >> 3, k8 = idx & 7;                                      \
      *reinterpret_cast<bf16x8*>(&As[row][k8 * 8]) = av[e];                  \
    }                                                                        \
    _Pragma("unroll") for (int e = 0; e < 2; ++e) {                          \
      int idx = tid + 256 * e;                                               \
      int row = idx >> 3, k8 = idx & 7;                                      \
      *reinterpret_cast<bf16x8*>(&Bs[row][k8 * 8]) = wv[e];                  \
    }                                                                        \
  } while (0)

  FC_LOAD(0);

  for (int kk = 0; kk < DMODEL; kk += 64) {
    __syncthreads();
    FC_WRITE();
    __syncthreads();
    if (kk + 64 < DMODEL) FC_LOAD(kk + 64);

#pragma unroll
    for (int ks2 = 0; ks2 < 2; ++ks2) {
      bf16x8 af[4], bfr[2];
#pragma unroll
      for (int i = 0; i < 4; ++i)
        af[i] = *reinterpret_cast<const bf16x8*>(
            &As[wm * 64 + 16 * i + lr][ks2 * 32 + g * 8]);
#pragma unroll
      for (int j = 0; j < 2; ++j)
        bfr[j] = *reinterpret_cast<const bf16x8*>(
            &Bs[wn * 32 + 16 * j + lr][ks2 * 32 + g * 8]);
#pragma unroll
      for (int i = 0; i < 4; ++i)
#pragma unroll
        for (int j = 0; j < 2; ++j)
          acc[i][j] = __builtin_amdgcn_mfma_f32_16x16x32_bf16(
              af[i], bfr[j], acc[i][j], 0, 0, 0);
    }
  }

#pragma unroll
  for (int i = 0; i < 4; ++i) {
    int m = m0 + wm * 64 + 16 * i + g * 4;
#pragma unroll
    for (int j = 0; j < 2; ++j) {
      int n = n0 + wn * 32 + 16 * j + lr;
      float* yp = Y + (size_t)m * DMODEL + n;
#pragma unroll
      for (int r = 0; r < 4; ++r) yp[(size_t)r * DMODEL] = acc[i][j][r] + bv[j];
    }
  }
#undef FC_LOAD
#undef FC_WRITE
}

extern "C" void kernel_launch(void* const* d_in, const int* in_sizes, int n_in,
                              void* d_out, int out_size, void* d_ws, size_t ws_size,
                              hipStream_t stream) {
  const float* q    = (const float*)d_in[0];
  const float* k    = (const float*)d_in[1];
  const float* v    = (const float*)d_in[2];
  const float* w    = (const float*)d_in[3];
  const float* bias = (const float*)d_in[4];
  float* out = (float*)d_out;

  char* ws = (char*)d_ws;
  __bf16* O   = (__bf16*)(ws);                  //  8 MB attention output
  __bf16* Kbf = (__bf16*)(ws + (8u << 20));     //  8 MB head-major K bf16
  __bf16* Vt  = (__bf16*)(ws + (16u << 20));    //  8 MB transposed V bf16
  __bf16* Wbf = (__bf16*)(ws + (24u << 20));    //  2 MB W bf16

  conv_all<<<dim3(3584), 256, 0, stream>>>(k, Kbf, v, Vt, w, Wbf);
  attn_kernel<<<dim3(1024), 512, 0, stream>>>(q, Kbf, Vt, O);
  fc_kernel<<<dim3(512), 256, 0, stream>>>(O, Wbf, bias, out);
}

// Round 23
// 87.922 us; speedup vs baseline: 1.0873x; 1.0873x over previous
//
#include <hip/hip_runtime.h>
#include <hip/hip_bf16.h>

#define BATCH 2
#define SEQ 2048
#define DMODEL 1024
#define NHEADS 16
#define HDIM 64
#define KVBLK 64
#define NCHUNK (SEQ / KVBLK)     // 32 total; 16 per KV-split
#define NITER (NCHUNK / 2)       // 16

// 0.125 (1/sqrt(64)) * log2(e): logits land directly in exp2 domain
#define QSCALE 0.180336880f
#define DEFER_THR 8.0f

typedef __bf16 bf16x8 __attribute__((ext_vector_type(8)));
typedef __bf16 bf16x4 __attribute__((ext_vector_type(4)));
typedef float f32x4 __attribute__((ext_vector_type(4)));
typedef float f32x16 __attribute__((ext_vector_type(16)));
typedef unsigned int uint2v __attribute__((ext_vector_type(2)));

union B8u { unsigned int u[4]; bf16x8 v; };

__device__ __forceinline__ unsigned int cvt_pk_bf16(float lo, float hi) {
  unsigned int d;
  asm("v_cvt_pk_bf16_f32 %0, %1, %2" : "=v"(d) : "v"(lo), "v"(hi));
  return d;
}

// a' = {a.lo32lanes, b.lo32lanes}; b' = {a.hi32lanes, b.hi32lanes}
__device__ __forceinline__ void permlane32_swap(unsigned &a, unsigned &b) {
  auto r = __builtin_amdgcn_permlane32_swap(a, b, false, false);
  unsigned tmp[2];
  __builtin_memcpy(tmp, &r, 8);
  a = tmp[0]; b = tmp[1];
}

// ---------------------------------------------------------------------------
// Fused prep (one launch) — byte-identical to R11/R17/R21 measured kernel.
// ---------------------------------------------------------------------------
__global__ __launch_bounds__(256)
void conv_all(const float* __restrict__ K, __bf16* __restrict__ Kbf,
              const float* __restrict__ V, __bf16* __restrict__ Vt,
              const float* __restrict__ W, __bf16* __restrict__ Wbf) {
  const int p = blockIdx.x;
  __shared__ __bf16 T[64][72];

  if (p < 2048) {
    const int t = p * 256 + threadIdx.x;
    const int d8 = t & 7, key = (t >> 3) & (SEQ - 1), g = t >> 14;
    const float* src = K + ((size_t)(g >> 4) * SEQ + key) * DMODEL +
                       (g & 15) * HDIM + d8 * 8;
    f32x4 a = *reinterpret_cast<const f32x4*>(src);
    f32x4 c = *reinterpret_cast<const f32x4*>(src + 4);
    bf16x8 o;
#pragma unroll
    for (int j = 0; j < 4; ++j) { o[j] = (__bf16)a[j]; o[4 + j] = (__bf16)c[j]; }
    *reinterpret_cast<bf16x8*>(Kbf + (size_t)t * 8) = o;
  } else if (p < 3072) {
    const int blk = p - 2048;                    // 1024
    const int g = blk >> 5, c0 = (blk & 31) * 64;
    const int b = g >> 4, h = g & 15;
    {
      const int key = threadIdx.x >> 2, dq = threadIdx.x & 3;
      const float* src = V + ((size_t)(b * SEQ) + c0 + key) * DMODEL +
                         h * HDIM + dq * 16;
#pragma unroll
      for (int i = 0; i < 4; ++i) {
        f32x4 v = *reinterpret_cast<const f32x4*>(src + 4 * i);
        bf16x4 o;
#pragma unroll
        for (int j = 0; j < 4; ++j) o[j] = (__bf16)v[j];
        *reinterpret_cast<bf16x4*>(&T[key][dq * 16 + 4 * i]) = o;
      }
    }
    __syncthreads();
    {
      const int d = threadIdx.x >> 2, kq = threadIdx.x & 3;
      bf16x8 r0, r1;
#pragma unroll
      for (int i = 0; i < 8; ++i) {
        r0[i] = T[kq * 16 + i][d];
        r1[i] = T[kq * 16 + 8 + i][d];
      }
      __bf16* dst = Vt + ((size_t)g * HDIM + d) * SEQ + c0 + kq * 16;
      *reinterpret_cast<bf16x8*>(dst) = r0;
      *reinterpret_cast<bf16x8*>(dst + 8) = r1;
    }
  } else {
    const int t = (p - 3072) * 256 + threadIdx.x;
    f32x4 a = *reinterpret_cast<const f32x4*>(W + (size_t)t * 8);
    f32x4 c = *reinterpret_cast<const f32x4*>(W + (size_t)t * 8 + 4);
    bf16x8 o;
#pragma unroll
    for (int j = 0; j < 4; ++j) { o[j] = (__bf16)a[j]; o[4 + j] = (__bf16)c[j]; }
    *reinterpret_cast<bf16x8*>(Wbf + (size_t)t * 8) = o;
  }
}

// ---------------------------------------------------------------------------
// Flash attention — byte-identical to the R21 measured kernel (best attn):
// 32x32 swapped structure + 2-way KV-split + XCD swizzle, single-buffered
// 33KB LDS with register-carried chunk prefetch.
// ---------------------------------------------------------------------------
__global__ __launch_bounds__(512, 4)
void attn_kernel(const float* __restrict__ Q, const __bf16* __restrict__ Kbf,
                 const __bf16* __restrict__ Vt, __bf16* __restrict__ O) {
  const int p = blockIdx.x;
  const int xcd = p & 7, slot = p >> 3;          // slot 0..63
  const int g = xcd + 8 * (slot >> 4);           // (b*16+h), 4 groups per XCD
  const int b = g >> 4, h = g & 15;
  const int q0 = (slot & 15) * 128;

  const int tid = threadIdx.x;
  const int wave = tid >> 6, lane = tid & 63;
  const int qg = wave & 3, ks = wave >> 2;
  const int l31 = lane & 31, hi = lane >> 5;
  const int ob = hi << 4;
  const int swz = (l31 & 7) << 4;

  __shared__ __align__(16) __bf16 SM[2][2][64 * 64];
  __shared__ float mlb[2][4][32];

  const int qrow = q0 + (qg << 5) + l31;
  const float* qp = Q + ((size_t)(b * SEQ + qrow)) * DMODEL + h * HDIM;
  bf16x8 qf[4];
#pragma unroll
  for (int kd = 0; kd < 4; ++kd) {
    f32x4 a = *reinterpret_cast<const f32x4*>(qp + kd * 16 + hi * 8);
    f32x4 c = *reinterpret_cast<const f32x4*>(qp + kd * 16 + hi * 8 + 4);
#pragma unroll
    for (int j = 0; j < 4; ++j) {
      qf[kd][j]     = (__bf16)(a[j] * QSCALE);
      qf[kd][4 + j] = (__bf16)(c[j] * QSCALE);
    }
  }

  f32x16 oacc0, oacc1;
#pragma unroll
  for (int r = 0; r < 16; ++r) { oacc0[r] = 0.f; oacc1[r] = 0.f; }
  float m_run = -1e30f, l_run = 0.f;

  const __bf16* kgb = Kbf + (size_t)g * SEQ * HDIM;
  const __bf16* vgb = Vt + (size_t)g * HDIM * SEQ;

  const int t2 = tid & 255;
  const int sk_key = t2 >> 2, sk_dq = t2 & 3;
  const int sv_dim = t2 >> 2, sv_kq = t2 & 3;
  const int ksw = (sk_key & 7) << 4;
  const int vsw = (sv_dim & 7) << 4;

  bf16x8 kr0, kr1, vr0, vr1;

#define STAGE_LOAD(C0)                                                        \
  do {                                                                        \
    const __bf16* kc = kgb + (size_t)(C0 + sk_key) * HDIM + sk_dq * 16;       \
    kr0 = *reinterpret_cast<const bf16x8*>(kc);                               \
    kr1 = *reinterpret_cast<const bf16x8*>(kc + 8);                           \
    const __bf16* vc = vgb + (size_t)sv_dim * SEQ + (C0) + sv_kq * 16;        \
    vr0 = *reinterpret_cast<const bf16x8*>(vc);                               \
    vr1 = *reinterpret_cast<const bf16x8*>(vc + 8);                           \
  } while (0)

#define STAGE_WRITE()                                                         \
  do {                                                                        \
    char* kdst = (char*)(&SM[ks][0][0]) + sk_key * 128;                       \
    *reinterpret_cast<bf16x8*>(kdst + (((sk_dq << 5)) ^ ksw)) = kr0;          \
    *reinterpret_cast<bf16x8*>(kdst + (((sk_dq << 5) | 16) ^ ksw)) = kr1;     \
    char* vdst = (char*)(&SM[ks][1][0]) + sv_dim * 128;                       \
    *reinterpret_cast<bf16x8*>(vdst + (((sv_kq << 5)) ^ vsw)) = vr0;          \
    *reinterpret_cast<bf16x8*>(vdst + (((sv_kq << 5) | 16) ^ vsw)) = vr1;     \
  } while (0)

  STAGE_LOAD(ks * NITER * KVBLK);
  STAGE_WRITE();
  __syncthreads();
  STAGE_LOAD((ks * NITER + 1) * KVBLK);

  for (int i = 0; i < NITER; ++i) {
    const char* kb = (const char*)(&SM[ks][0][0]);
    const char* vb = (const char*)(&SM[ks][1][0]);

    f32x16 s0, s1;
#pragma unroll
    for (int r = 0; r < 16; ++r) { s0[r] = 0.f; s1[r] = 0.f; }
    __builtin_amdgcn_s_setprio(1);
#pragma unroll
    for (int kd = 0; kd < 4; ++kd) {
      bf16x8 a0 = *reinterpret_cast<const bf16x8*>(
          kb + l31 * 128 + (((kd << 5) | ob) ^ swz));
      bf16x8 a1 = *reinterpret_cast<const bf16x8*>(
          kb + (32 + l31) * 128 + (((kd << 5) | ob) ^ swz));
      s0 = __builtin_amdgcn_mfma_f32_32x32x16_bf16(a0, qf[kd], s0, 0, 0, 0);
      s1 = __builtin_amdgcn_mfma_f32_32x32x16_bf16(a1, qf[kd], s1, 0, 0, 0);
    }
    __builtin_amdgcn_s_setprio(0);

    float m8[8];
#pragma unroll
    for (int r = 0; r < 8; ++r)
      m8[r] = fmaxf(fmaxf(s0[r], s0[r + 8]), fmaxf(s1[r], s1[r + 8]));
    float pm = fmaxf(fmaxf(fmaxf(m8[0], m8[1]), fmaxf(m8[2], m8[3])),
                     fmaxf(fmaxf(m8[4], m8[5]), fmaxf(m8[6], m8[7])));
    pm = fmaxf(pm, __shfl_xor(pm, 32, 64));

    if (!__all(pm <= m_run + DEFER_THR)) {
      float mu = fmaxf(m_run, pm);
      float al = __builtin_amdgcn_exp2f(m_run - mu);
      m_run = mu;
      l_run *= al;
#pragma unroll
      for (int r = 0; r < 16; ++r) { oacc0[r] *= al; oacc1[r] *= al; }
    }

#pragma unroll
    for (int r = 0; r < 16; ++r) {
      s0[r] = __builtin_amdgcn_exp2f(s0[r] - m_run);
      s1[r] = __builtin_amdgcn_exp2f(s1[r] - m_run);
    }
    float t8[8];
#pragma unroll
    for (int r = 0; r < 8; ++r)
      t8[r] = (s0[r] + s0[r + 8]) + (s1[r] + s1[r + 8]);
    float ts = ((t8[0] + t8[1]) + (t8[2] + t8[3])) +
               ((t8[4] + t8[5]) + (t8[6] + t8[7]));
    ts += __shfl_xor(ts, 32, 64);
    l_run += ts;

    B8u pfr[4];
#pragma unroll
    for (int kq = 0; kq < 4; ++kq) {
      f32x16 ps = (kq < 2) ? s0 : s1;
      const int r0 = (kq & 1) * 8;
      unsigned lo0 = cvt_pk_bf16(ps[r0 + 0], ps[r0 + 1]);
      unsigned lo1 = cvt_pk_bf16(ps[r0 + 2], ps[r0 + 3]);
      unsigned h0  = cvt_pk_bf16(ps[r0 + 4], ps[r0 + 5]);
      unsigned h1  = cvt_pk_bf16(ps[r0 + 6], ps[r0 + 7]);
      permlane32_swap(lo0, h0);
      permlane32_swap(lo1, h1);
      pfr[kq].u[0] = lo0; pfr[kq].u[1] = lo1;
      pfr[kq].u[2] = h0;  pfr[kq].u[3] = h1;
    }

    __builtin_amdgcn_s_setprio(1);
#pragma unroll
    for (int kq = 0; kq < 4; ++kq) {
      bf16x8 v0 = *reinterpret_cast<const bf16x8*>(
          vb + l31 * 128 + (((kq << 5) | ob) ^ swz));
      bf16x8 v1 = *reinterpret_cast<const bf16x8*>(
          vb + (32 + l31) * 128 + (((kq << 5) | ob) ^ swz));
      oacc0 = __builtin_amdgcn_mfma_f32_32x32x16_bf16(v0, pfr[kq].v, oacc0, 0, 0, 0);
      oacc1 = __builtin_amdgcn_mfma_f32_32x32x16_bf16(v1, pfr[kq].v, oacc1, 0, 0, 0);
    }
    __builtin_amdgcn_s_setprio(0);

    __syncthreads();
    if (i + 1 < NITER) {
      STAGE_WRITE();
      if (i + 2 < NITER) STAGE_LOAD((ks * NITER + i + 2) * KVBLK);
    }
    __syncthreads();
  }

  float* Ob = (float*)&SM[0][0][0];          // [4][64][32] = 32 KB

  if (ks == 1) {
    if (hi == 0) { mlb[0][qg][l31] = m_run; mlb[1][qg][l31] = l_run; }
#pragma unroll
    for (int dt = 0; dt < 2; ++dt) {
      f32x16 oa = dt ? oacc1 : oacc0;
#pragma unroll
      for (int r = 0; r < 16; ++r) {
        int dim = dt * 32 + (r & 3) + 8 * (r >> 2) + 4 * hi;
        Ob[(qg * 64 + dim) * 32 + l31] = oa[r];
      }
    }
  }
  __syncthreads();

  if (ks == 0) {
    float m1 = mlb[0][qg][l31], l1 = mlb[1][qg][l31];
    float m = fmaxf(m_run, m1);
    float a0 = __builtin_amdgcn_exp2f(m_run - m);
    float a1 = __builtin_amdgcn_exp2f(m1 - m);
    const float inv = 1.0f / (a0 * l_run + a1 * l1);
    __bf16* op = O + ((size_t)(b * SEQ + qrow)) * DMODEL + h * HDIM;
#pragma unroll
    for (int dt = 0; dt < 2; ++dt) {
      f32x16 oa = dt ? oacc1 : oacc0;
#pragma unroll
      for (int a = 0; a < 4; ++a) {
        float e[4];
#pragma unroll
        for (int j = 0; j < 4; ++j) {
          int r = 4 * a + j;
          int dim = dt * 32 + (r & 3) + 8 * (r >> 2) + 4 * hi;
          float opart = Ob[(qg * 64 + dim) * 32 + l31];
          e[j] = (oa[r] * a0 + opart * a1) * inv;
        }
        uint2v w;
        w[0] = cvt_pk_bf16(e[0], e[1]);
        w[1] = cvt_pk_bf16(e[2], e[3]);
        *reinterpret_cast<uint2v*>((char*)op + (dt * 32 + a * 8 + hi * 4) * 2) = w;
      }
    }
  }
#undef STAGE_LOAD
#undef STAGE_WRITE
}

// ---------------------------------------------------------------------------
// FC: Y[4096][1024] = X(bf16) @ Wbf^T + bias, fp32 out.
// NEW: 128x32 tile, BK=64, 4 waves (2x2, wave = 64x16), grid 1024 =
// 4 blocks/CU (doubled TLP hides staging latency). T14 reg prefetch kept.
// Per-XCD: X 4 m-panels (1MB) + W 2MB < 4MB L2.
// ---------------------------------------------------------------------------
__global__ __launch_bounds__(256)
void fc_kernel(const __bf16* __restrict__ X, const __bf16* __restrict__ W,
               const float* __restrict__ bias, float* __restrict__ Y) {
  const int p = blockIdx.x;
  const int xcd = p & 7, slot = p >> 3;            // slot 0..127
  const int m0 = (xcd + 8 * (slot >> 5)) * 128;    // 4 m-tiles per XCD
  const int n0 = (slot & 31) * 32;

  const int tid = threadIdx.x;
  const int wave = tid >> 6, lane = tid & 63;
  const int g = lane >> 4, lr = lane & 15;
  const int wm = wave >> 1, wn = wave & 1;

  __shared__ __bf16 As[128][72];   // [m][k], +8 pad (18.4 KB)
  __shared__ __bf16 Bs[32][72];    // [n][k] (4.6 KB)

  f32x4 acc[4];
#pragma unroll
  for (int i = 0; i < 4; ++i) acc[i] = (f32x4){0.f, 0.f, 0.f, 0.f};

  const float bv = bias[n0 + wn * 16 + lr];

  bf16x8 av[4], wv;

#define FC_LOAD(KK)                                                          \
  do {                                                                       \
    _Pragma("unroll") for (int e = 0; e < 4; ++e) {                          \
      int idx = tid + 256 * e;                                               \
      int row = idx >> 3, k8 = idx & 7;                                      \
      av[e] = *reinterpret_cast<const bf16x8*>(                              \
          X + (size_t)(m0 + row) * DMODEL + (KK) + k8 * 8);                  \
    }                                                                        \
    {                                                                        \
      int row = tid >> 3, k8 = tid & 7;                                      \
      wv = *reinterpret_cast<const bf16x8*>(                                 \
          W + (size_t)(n0 + row) * DMODEL + (KK) + k8 * 8);                  \
    }                                                                        \
  } while (0)

#define FC_WRITE()                                                           \
  do {                                                                       \
    _Pragma("unroll") for (int e = 0; e < 4; ++e) {                          \
      int idx = tid + 256 * e;                                               \
      int row = idx >> 3, k8 = idx & 7;                                      \
      *reinterpret_cast<bf16x8*>(&As[row][k8 * 8]) = av[e];                  \
    }                                                                        \
    {                                                                        \
      int row = tid >> 3, k8 = tid & 7;                                      \
      *reinterpret_cast<bf16x8*>(&Bs[row][k8 * 8]) = wv;                     \
    }                                                                        \
  } while (0)

  FC_LOAD(0);

  for (int kk = 0; kk < DMODEL; kk += 64) {
    __syncthreads();
    FC_WRITE();
    __syncthreads();
    if (kk + 64 < DMODEL) FC_LOAD(kk + 64);

#pragma unroll
    for (int ks2 = 0; ks2 < 2; ++ks2) {
      bf16x8 bfr = *reinterpret_cast<const bf16x8*>(
          &Bs[wn * 16 + lr][ks2 * 32 + g * 8]);
#pragma unroll
      for (int i = 0; i < 4; ++i) {
        bf16x8 af = *reinterpret_cast<const bf16x8*>(
            &As[wm * 64 + 16 * i + lr][ks2 * 32 + g * 8]);
        acc[i] = __builtin_amdgcn_mfma_f32_16x16x32_bf16(af, bfr, acc[i], 0, 0, 0);
      }
    }
  }

#pragma unroll
  for (int i = 0; i < 4; ++i) {
    int m = m0 + wm * 64 + 16 * i + g * 4;
    int n = n0 + wn * 16 + lr;
    float* yp = Y + (size_t)m * DMODEL + n;
#pragma unroll
    for (int r = 0; r < 4; ++r) yp[(size_t)r * DMODEL] = acc[i][r] + bv;
  }
#undef FC_LOAD
#undef FC_WRITE
}

extern "C" void kernel_launch(void* const* d_in, const int* in_sizes, int n_in,
                              void* d_out, int out_size, void* d_ws, size_t ws_size,
                              hipStream_t stream) {
  const float* q    = (const float*)d_in[0];
  const float* k    = (const float*)d_in[1];
  const float* v    = (const float*)d_in[2];
  const float* w    = (const float*)d_in[3];
  const float* bias = (const float*)d_in[4];
  float* out = (float*)d_out;

  char* ws = (char*)d_ws;
  __bf16* O   = (__bf16*)(ws);                  //  8 MB attention output
  __bf16* Kbf = (__bf16*)(ws + (8u << 20));     //  8 MB head-major K bf16
  __bf16* Vt  = (__bf16*)(ws + (16u << 20));    //  8 MB transposed V bf16
  __bf16* Wbf = (__bf16*)(ws + (24u << 20));    //  2 MB W bf16

  conv_all<<<dim3(3584), 256, 0, stream>>>(k, Kbf, v, Vt, w, Wbf);
  attn_kernel<<<dim3(512), 512, 0, stream>>>(q, Kbf, Vt, O);
  fc_kernel<<<dim3(1024), 256, 0, stream>>>(O, Wbf, bias, out);
}

// Round 24
// 83.802 us; speedup vs baseline: 1.1407x; 1.0492x over previous
//
#include <hip/hip_runtime.h>
#include <hip/hip_bf16.h>

#define BATCH 2
#define SEQ 2048
#define DMODEL 1024
#define NHEADS 16
#define HDIM 64
#define KVBLK 64
#define NCHUNK (SEQ / KVBLK)     // 32 total; 16 per KV-split
#define NITER (NCHUNK / 2)       // 16

// 0.125 (1/sqrt(64)) * log2(e): logits land directly in exp2 domain
#define QSCALE 0.180336880f
#define DEFER_THR 8.0f

typedef __bf16 bf16x8 __attribute__((ext_vector_type(8)));
typedef __bf16 bf16x4 __attribute__((ext_vector_type(4)));
typedef float f32x4 __attribute__((ext_vector_type(4)));
typedef float f32x16 __attribute__((ext_vector_type(16)));
typedef unsigned int uint2v __attribute__((ext_vector_type(2)));

union B8u { unsigned int u[4]; bf16x8 v; };

__device__ __forceinline__ unsigned int cvt_pk_bf16(float lo, float hi) {
  unsigned int d;
  asm("v_cvt_pk_bf16_f32 %0, %1, %2" : "=v"(d) : "v"(lo), "v"(hi));
  return d;
}

// a' = {a.lo32lanes, b.lo32lanes}; b' = {a.hi32lanes, b.hi32lanes}
__device__ __forceinline__ void permlane32_swap(unsigned &a, unsigned &b) {
  auto r = __builtin_amdgcn_permlane32_swap(a, b, false, false);
  unsigned tmp[2];
  __builtin_memcpy(tmp, &r, 8);
  a = tmp[0]; b = tmp[1];
}

// ---------------------------------------------------------------------------
// Fused prep (one launch) — byte-identical to R11/R17/R21 measured kernel.
// ---------------------------------------------------------------------------
__global__ __launch_bounds__(256)
void conv_all(const float* __restrict__ K, __bf16* __restrict__ Kbf,
              const float* __restrict__ V, __bf16* __restrict__ Vt,
              const float* __restrict__ W, __bf16* __restrict__ Wbf) {
  const int p = blockIdx.x;
  __shared__ __bf16 T[64][72];

  if (p < 2048) {
    const int t = p * 256 + threadIdx.x;
    const int d8 = t & 7, key = (t >> 3) & (SEQ - 1), g = t >> 14;
    const float* src = K + ((size_t)(g >> 4) * SEQ + key) * DMODEL +
                       (g & 15) * HDIM + d8 * 8;
    f32x4 a = *reinterpret_cast<const f32x4*>(src);
    f32x4 c = *reinterpret_cast<const f32x4*>(src + 4);
    bf16x8 o;
#pragma unroll
    for (int j = 0; j < 4; ++j) { o[j] = (__bf16)a[j]; o[4 + j] = (__bf16)c[j]; }
    *reinterpret_cast<bf16x8*>(Kbf + (size_t)t * 8) = o;
  } else if (p < 3072) {
    const int blk = p - 2048;                    // 1024
    const int g = blk >> 5, c0 = (blk & 31) * 64;
    const int b = g >> 4, h = g & 15;
    {
      const int key = threadIdx.x >> 2, dq = threadIdx.x & 3;
      const float* src = V + ((size_t)(b * SEQ) + c0 + key) * DMODEL +
                         h * HDIM + dq * 16;
#pragma unroll
      for (int i = 0; i < 4; ++i) {
        f32x4 v = *reinterpret_cast<const f32x4*>(src + 4 * i);
        bf16x4 o;
#pragma unroll
        for (int j = 0; j < 4; ++j) o[j] = (__bf16)v[j];
        *reinterpret_cast<bf16x4*>(&T[key][dq * 16 + 4 * i]) = o;
      }
    }
    __syncthreads();
    {
      const int d = threadIdx.x >> 2, kq = threadIdx.x & 3;
      bf16x8 r0, r1;
#pragma unroll
      for (int i = 0; i < 8; ++i) {
        r0[i] = T[kq * 16 + i][d];
        r1[i] = T[kq * 16 + 8 + i][d];
      }
      __bf16* dst = Vt + ((size_t)g * HDIM + d) * SEQ + c0 + kq * 16;
      *reinterpret_cast<bf16x8*>(dst) = r0;
      *reinterpret_cast<bf16x8*>(dst + 8) = r1;
    }
  } else {
    const int t = (p - 3072) * 256 + threadIdx.x;
    f32x4 a = *reinterpret_cast<const f32x4*>(W + (size_t)t * 8);
    f32x4 c = *reinterpret_cast<const f32x4*>(W + (size_t)t * 8 + 4);
    bf16x8 o;
#pragma unroll
    for (int j = 0; j < 4; ++j) { o[j] = (__bf16)a[j]; o[4 + j] = (__bf16)c[j]; }
    *reinterpret_cast<bf16x8*>(Wbf + (size_t)t * 8) = o;
  }
}

// ---------------------------------------------------------------------------
// Flash attention — byte-identical to the R21 measured kernel (best attn):
// 32x32 swapped structure + 2-way KV-split + XCD swizzle, single-buffered
// 33KB LDS with register-carried chunk prefetch.
// ---------------------------------------------------------------------------
__global__ __launch_bounds__(512, 4)
void attn_kernel(const float* __restrict__ Q, const __bf16* __restrict__ Kbf,
                 const __bf16* __restrict__ Vt, __bf16* __restrict__ O) {
  const int p = blockIdx.x;
  const int xcd = p & 7, slot = p >> 3;          // slot 0..63
  const int g = xcd + 8 * (slot >> 4);           // (b*16+h), 4 groups per XCD
  const int b = g >> 4, h = g & 15;
  const int q0 = (slot & 15) * 128;

  const int tid = threadIdx.x;
  const int wave = tid >> 6, lane = tid & 63;
  const int qg = wave & 3, ks = wave >> 2;
  const int l31 = lane & 31, hi = lane >> 5;
  const int ob = hi << 4;
  const int swz = (l31 & 7) << 4;

  __shared__ __align__(16) __bf16 SM[2][2][64 * 64];
  __shared__ float mlb[2][4][32];

  const int qrow = q0 + (qg << 5) + l31;
  const float* qp = Q + ((size_t)(b * SEQ + qrow)) * DMODEL + h * HDIM;
  bf16x8 qf[4];
#pragma unroll
  for (int kd = 0; kd < 4; ++kd) {
    f32x4 a = *reinterpret_cast<const f32x4*>(qp + kd * 16 + hi * 8);
    f32x4 c = *reinterpret_cast<const f32x4*>(qp + kd * 16 + hi * 8 + 4);
#pragma unroll
    for (int j = 0; j < 4; ++j) {
      qf[kd][j]     = (__bf16)(a[j] * QSCALE);
      qf[kd][4 + j] = (__bf16)(c[j] * QSCALE);
    }
  }

  f32x16 oacc0, oacc1;
#pragma unroll
  for (int r = 0; r < 16; ++r) { oacc0[r] = 0.f; oacc1[r] = 0.f; }
  float m_run = -1e30f, l_run = 0.f;

  const __bf16* kgb = Kbf + (size_t)g * SEQ * HDIM;
  const __bf16* vgb = Vt + (size_t)g * HDIM * SEQ;

  const int t2 = tid & 255;
  const int sk_key = t2 >> 2, sk_dq = t2 & 3;
  const int sv_dim = t2 >> 2, sv_kq = t2 & 3;
  const int ksw = (sk_key & 7) << 4;
  const int vsw = (sv_dim & 7) << 4;

  bf16x8 kr0, kr1, vr0, vr1;

#define STAGE_LOAD(C0)                                                        \
  do {                                                                        \
    const __bf16* kc = kgb + (size_t)(C0 + sk_key) * HDIM + sk_dq * 16;       \
    kr0 = *reinterpret_cast<const bf16x8*>(kc);                               \
    kr1 = *reinterpret_cast<const bf16x8*>(kc + 8);                           \
    const __bf16* vc = vgb + (size_t)sv_dim * SEQ + (C0) + sv_kq * 16;        \
    vr0 = *reinterpret_cast<const bf16x8*>(vc);                               \
    vr1 = *reinterpret_cast<const bf16x8*>(vc + 8);                           \
  } while (0)

#define STAGE_WRITE()                                                         \
  do {                                                                        \
    char* kdst = (char*)(&SM[ks][0][0]) + sk_key * 128;                       \
    *reinterpret_cast<bf16x8*>(kdst + (((sk_dq << 5)) ^ ksw)) = kr0;          \
    *reinterpret_cast<bf16x8*>(kdst + (((sk_dq << 5) | 16) ^ ksw)) = kr1;     \
    char* vdst = (char*)(&SM[ks][1][0]) + sv_dim * 128;                       \
    *reinterpret_cast<bf16x8*>(vdst + (((sv_kq << 5)) ^ vsw)) = vr0;          \
    *reinterpret_cast<bf16x8*>(vdst + (((sv_kq << 5) | 16) ^ vsw)) = vr1;     \
  } while (0)

  STAGE_LOAD(ks * NITER * KVBLK);
  STAGE_WRITE();
  __syncthreads();
  STAGE_LOAD((ks * NITER + 1) * KVBLK);

  for (int i = 0; i < NITER; ++i) {
    const char* kb = (const char*)(&SM[ks][0][0]);
    const char* vb = (const char*)(&SM[ks][1][0]);

    f32x16 s0, s1;
#pragma unroll
    for (int r = 0; r < 16; ++r) { s0[r] = 0.f; s1[r] = 0.f; }
    __builtin_amdgcn_s_setprio(1);
#pragma unroll
    for (int kd = 0; kd < 4; ++kd) {
      bf16x8 a0 = *reinterpret_cast<const bf16x8*>(
          kb + l31 * 128 + (((kd << 5) | ob) ^ swz));
      bf16x8 a1 = *reinterpret_cast<const bf16x8*>(
          kb + (32 + l31) * 128 + (((kd << 5) | ob) ^ swz));
      s0 = __builtin_amdgcn_mfma_f32_32x32x16_bf16(a0, qf[kd], s0, 0, 0, 0);
      s1 = __builtin_amdgcn_mfma_f32_32x32x16_bf16(a1, qf[kd], s1, 0, 0, 0);
    }
    __builtin_amdgcn_s_setprio(0);

    float m8[8];
#pragma unroll
    for (int r = 0; r < 8; ++r)
      m8[r] = fmaxf(fmaxf(s0[r], s0[r + 8]), fmaxf(s1[r], s1[r + 8]));
    float pm = fmaxf(fmaxf(fmaxf(m8[0], m8[1]), fmaxf(m8[2], m8[3])),
                     fmaxf(fmaxf(m8[4], m8[5]), fmaxf(m8[6], m8[7])));
    pm = fmaxf(pm, __shfl_xor(pm, 32, 64));

    if (!__all(pm <= m_run + DEFER_THR)) {
      float mu = fmaxf(m_run, pm);
      float al = __builtin_amdgcn_exp2f(m_run - mu);
      m_run = mu;
      l_run *= al;
#pragma unroll
      for (int r = 0; r < 16; ++r) { oacc0[r] *= al; oacc1[r] *= al; }
    }

#pragma unroll
    for (int r = 0; r < 16; ++r) {
      s0[r] = __builtin_amdgcn_exp2f(s0[r] - m_run);
      s1[r] = __builtin_amdgcn_exp2f(s1[r] - m_run);
    }
    float t8[8];
#pragma unroll
    for (int r = 0; r < 8; ++r)
      t8[r] = (s0[r] + s0[r + 8]) + (s1[r] + s1[r + 8]);
    float ts = ((t8[0] + t8[1]) + (t8[2] + t8[3])) +
               ((t8[4] + t8[5]) + (t8[6] + t8[7]));
    ts += __shfl_xor(ts, 32, 64);
    l_run += ts;

    B8u pfr[4];
#pragma unroll
    for (int kq = 0; kq < 4; ++kq) {
      f32x16 ps = (kq < 2) ? s0 : s1;
      const int r0 = (kq & 1) * 8;
      unsigned lo0 = cvt_pk_bf16(ps[r0 + 0], ps[r0 + 1]);
      unsigned lo1 = cvt_pk_bf16(ps[r0 + 2], ps[r0 + 3]);
      unsigned h0  = cvt_pk_bf16(ps[r0 + 4], ps[r0 + 5]);
      unsigned h1  = cvt_pk_bf16(ps[r0 + 6], ps[r0 + 7]);
      permlane32_swap(lo0, h0);
      permlane32_swap(lo1, h1);
      pfr[kq].u[0] = lo0; pfr[kq].u[1] = lo1;
      pfr[kq].u[2] = h0;  pfr[kq].u[3] = h1;
    }

    __builtin_amdgcn_s_setprio(1);
#pragma unroll
    for (int kq = 0; kq < 4; ++kq) {
      bf16x8 v0 = *reinterpret_cast<const bf16x8*>(
          vb + l31 * 128 + (((kq << 5) | ob) ^ swz));
      bf16x8 v1 = *reinterpret_cast<const bf16x8*>(
          vb + (32 + l31) * 128 + (((kq << 5) | ob) ^ swz));
      oacc0 = __builtin_amdgcn_mfma_f32_32x32x16_bf16(v0, pfr[kq].v, oacc0, 0, 0, 0);
      oacc1 = __builtin_amdgcn_mfma_f32_32x32x16_bf16(v1, pfr[kq].v, oacc1, 0, 0, 0);
    }
    __builtin_amdgcn_s_setprio(0);

    __syncthreads();
    if (i + 1 < NITER) {
      STAGE_WRITE();
      if (i + 2 < NITER) STAGE_LOAD((ks * NITER + i + 2) * KVBLK);
    }
    __syncthreads();
  }

  float* Ob = (float*)&SM[0][0][0];          // [4][64][32] = 32 KB

  if (ks == 1) {
    if (hi == 0) { mlb[0][qg][l31] = m_run; mlb[1][qg][l31] = l_run; }
#pragma unroll
    for (int dt = 0; dt < 2; ++dt) {
      f32x16 oa = dt ? oacc1 : oacc0;
#pragma unroll
      for (int r = 0; r < 16; ++r) {
        int dim = dt * 32 + (r & 3) + 8 * (r >> 2) + 4 * hi;
        Ob[(qg * 64 + dim) * 32 + l31] = oa[r];
      }
    }
  }
  __syncthreads();

  if (ks == 0) {
    float m1 = mlb[0][qg][l31], l1 = mlb[1][qg][l31];
    float m = fmaxf(m_run, m1);
    float a0 = __builtin_amdgcn_exp2f(m_run - m);
    float a1 = __builtin_amdgcn_exp2f(m1 - m);
    const float inv = 1.0f / (a0 * l_run + a1 * l1);
    __bf16* op = O + ((size_t)(b * SEQ + qrow)) * DMODEL + h * HDIM;
#pragma unroll
    for (int dt = 0; dt < 2; ++dt) {
      f32x16 oa = dt ? oacc1 : oacc0;
#pragma unroll
      for (int a = 0; a < 4; ++a) {
        float e[4];
#pragma unroll
        for (int j = 0; j < 4; ++j) {
          int r = 4 * a + j;
          int dim = dt * 32 + (r & 3) + 8 * (r >> 2) + 4 * hi;
          float opart = Ob[(qg * 64 + dim) * 32 + l31];
          e[j] = (oa[r] * a0 + opart * a1) * inv;
        }
        uint2v w;
        w[0] = cvt_pk_bf16(e[0], e[1]);
        w[1] = cvt_pk_bf16(e[2], e[3]);
        *reinterpret_cast<uint2v*>((char*)op + (dt * 32 + a * 8 + hi * 4) * 2) = w;
      }
    }
  }
#undef STAGE_LOAD
#undef STAGE_WRITE
}

// ---------------------------------------------------------------------------
// FC: Y[4096][1024] = X(bf16) @ Wbf^T + bias, fp32 out.
// 128x64 tile, BK=64, 4 waves (2x2), 512 blocks = 2/CU, T14 reg prefetch.
// (byte-identical to R20/R21 measured kernel)
// ---------------------------------------------------------------------------
__global__ __launch_bounds__(256)
void fc_kernel(const __bf16* __restrict__ X, const __bf16* __restrict__ W,
               const float* __restrict__ bias, float* __restrict__ Y) {
  const int p = blockIdx.x;
  const int xcd = p & 7, slot = p >> 3;            // slot 0..63
  const int m0 = (xcd + 8 * (slot >> 4)) * 128;    // 4 m-tiles per XCD
  const int n0 = (slot & 15) * 64;

  const int tid = threadIdx.x;
  const int wave = tid >> 6, lane = tid & 63;
  const int g = lane >> 4, lr = lane & 15;
  const int wm = wave >> 1, wn = wave & 1;

  __shared__ __bf16 As[128][72];   // [m][k], +8 pad
  __shared__ __bf16 Bs[64][72];    // [n][k]

  f32x4 acc[4][2];
#pragma unroll
  for (int i = 0; i < 4; ++i)
#pragma unroll
    for (int j = 0; j < 2; ++j) acc[i][j] = (f32x4){0.f, 0.f, 0.f, 0.f};

  float bv[2];
#pragma unroll
  for (int j = 0; j < 2; ++j) bv[j] = bias[n0 + wn * 32 + 16 * j + lr];

  bf16x8 av[4], wv[2];

#define FC_LOAD(KK)                                                          \
  do {                                                                       \
    _Pragma("unroll") for (int e = 0; e < 4; ++e) {                          \
      int idx = tid + 256 * e;                                               \
      int row = idx >> 3, k8 = idx & 7;                                      \
      av[e] = *reinterpret_cast<const bf16x8*>(                              \
          X + (size_t)(m0 + row) * DMODEL + (KK) + k8 * 8);                  \
    }                                                                        \
    _Pragma("unroll") for (int e = 0; e < 2; ++e) {                          \
      int idx = tid + 256 * e;                                               \
      int row = idx >> 3, k8 = idx & 7;                                      \
      wv[e] = *reinterpret_cast<const bf16x8*>(                              \
          W + (size_t)(n0 + row) * DMODEL + (KK) + k8 * 8);                  \
    }                                                                        \
  } while (0)

#define FC_WRITE()                                                           \
  do {                                                                       \
    _Pragma("unroll") for (int e = 0; e < 4; ++e) {                          \
      int idx = tid + 256 * e;                                               \
      int row = idx >> 3, k8 = idx & 7;                                      \
      *reinterpret_cast<bf16x8*>(&As[row][k8 * 8]) = av[e];                  \
    }                                                                        \
    _Pragma("unroll") for (int e = 0; e < 2; ++e) {                          \
      int idx = tid + 256 * e;                                               \
      int row = idx >> 3, k8 = idx & 7;                                      \
      *reinterpret_cast<bf16x8*>(&Bs[row][k8 * 8]) = wv[e];                  \
    }                                                                        \
  } while (0)

  FC_LOAD(0);

  for (int kk = 0; kk < DMODEL; kk += 64) {
    __syncthreads();
    FC_WRITE();
    __syncthreads();
    if (kk + 64 < DMODEL) FC_LOAD(kk + 64);

#pragma unroll
    for (int ks2 = 0; ks2 < 2; ++ks2) {
      bf16x8 af[4], bfr[2];
#pragma unroll
      for (int i = 0; i < 4; ++i)
        af[i] = *reinterpret_cast<const bf16x8*>(
            &As[wm * 64 + 16 * i + lr][ks2 * 32 + g * 8]);
#pragma unroll
      for (int j = 0; j < 2; ++j)
        bfr[j] = *reinterpret_cast<const bf16x8*>(
            &Bs[wn * 32 + 16 * j + lr][ks2 * 32 + g * 8]);
#pragma unroll
      for (int i = 0; i < 4; ++i)
#pragma unroll
        for (int j = 0; j < 2; ++j)
          acc[i][j] = __builtin_amdgcn_mfma_f32_16x16x32_bf16(
              af[i], bfr[j], acc[i][j], 0, 0, 0);
    }
  }

#pragma unroll
  for (int i = 0; i < 4; ++i) {
    int m = m0 + wm * 64 + 16 * i + g * 4;
#pragma unroll
    for (int j = 0; j < 2; ++j) {
      int n = n0 + wn * 32 + 16 * j + lr;
      float* yp = Y + (size_t)m * DMODEL + n;
#pragma unroll
      for (int r = 0; r < 4; ++r) yp[(size_t)r * DMODEL] = acc[i][j][r] + bv[j];
    }
  }
#undef FC_LOAD
#undef FC_WRITE
}

extern "C" void kernel_launch(void* const* d_in, const int* in_sizes, int n_in,
                              void* d_out, int out_size, void* d_ws, size_t ws_size,
                              hipStream_t stream) {
  const float* q    = (const float*)d_in[0];
  const float* k    = (const float*)d_in[1];
  const float* v    = (const float*)d_in[2];
  const float* w    = (const float*)d_in[3];
  const float* bias = (const float*)d_in[4];
  float* out = (float*)d_out;

  char* ws = (char*)d_ws;
  __bf16* O   = (__bf16*)(ws);                  //  8 MB attention output
  __bf16* Kbf = (__bf16*)(ws + (8u << 20));     //  8 MB head-major K bf16
  __bf16* Vt  = (__bf16*)(ws + (16u << 20));    //  8 MB transposed V bf16
  __bf16* Wbf = (__bf16*)(ws + (24u << 20));    //  2 MB W bf16

  conv_all<<<dim3(3584), 256, 0, stream>>>(k, Kbf, v, Vt, w, Wbf);
  attn_kernel<<<dim3(512), 512, 0, stream>>>(q, Kbf, Vt, O);
  fc_kernel<<<dim3(512), 256, 0, stream>>>(O, Wbf, bias, out);
}